// Round 9
// baseline (466.199 us; speedup 1.0000x reference)
//
#include <hip/hip_runtime.h>

#define M_TOTAL   2000000
#define NT        512
#define K1_BLOCKS 1024
#define K3_BLOCKS 2048

__device__ __forceinline__ float rlf(float v, int l) {
    union { float f; int i; } u; u.f = v;
    u.i = __builtin_amdgcn_readlane(u.i, l);
    return u.f;
}

// Barrier with LDS-only drain: in-loop cross-thread data is exclusively LDS,
// so vmcnt (global outL stores / gum / Rtab loads) never needs draining.
__device__ __forceinline__ void bar_lds() {
    asm volatile("s_waitcnt lgkmcnt(0)" ::: "memory");
    __builtin_amdgcn_s_barrier();
    asm volatile("" ::: "memory");
}

// DPP helpers (register-crossbar cross-lane, ~4cy vs ~100cy for ds_bpermute shuffles).
#define DPPMAXU(m, ctrl) { unsigned _d = (unsigned)__builtin_amdgcn_update_dpp(0, (int)(m), (ctrl), 0xF, 0xF, true); \
                           if (_d > (m)) (m) = _d; }
#define DPPADDF(s, ctrl) { float _d = __int_as_float(__builtin_amdgcn_update_dpp(0, __float_as_int(s), (ctrl), 0xF, 0xF, true)); \
                           (s) += _d; }
// quad_perm controls: xor1 = [1,0,3,2] = 0xB1 ; xor2 = [2,3,0,1] = 0x4E
#define QP_XOR1 0xB1
#define QP_XOR2 0x4E

__device__ __forceinline__ unsigned orderf(float f) {
    unsigned u = __float_as_uint(f);
    return u ^ (((unsigned)((int)u >> 31)) | 0x80000000u);   // monotone float->uint
}

__device__ __forceinline__ uint2 pick2(uint2 a, uint2 b) {
    // larger key wins; equal key -> smaller index (first-index tiebreak)
    bool takeb = (b.x > a.x) || (b.x == a.x && b.y < a.y);
    return takeb ? b : a;
}

#define REP16(M)  M(0) M(1) M(2) M(3) M(4) M(5) M(6) M(7) M(8) M(9) M(10) M(11) M(12) M(13) M(14) M(15)
#define REP16B(M) M(16) M(17) M(18) M(19) M(20) M(21) M(22) M(23) M(24) M(25) M(26) M(27) M(28) M(29) M(30) M(31)

// Volatile load of 4 consecutive floats: performed exactly once, where written.
#define VLD4(dst, base, c) { const volatile float* _p = (base) + 4*(c); \
    dst.x = _p[0]; dst.y = _p[1]; dst.z = _p[2]; dst.w = _p[3]; }

// -------------------- K_front: fused reduce (blocks 0..1023) + expm (1024..1535) + relayout (1536..2051) --------------------
extern "C" __global__ __launch_bounds__(256)
void k_front(const float* __restrict__ emb, const float* __restrict__ vsrc,
             const float* __restrict__ vtgt, double* __restrict__ partials,
             const float* __restrict__ tc, float* __restrict__ Rtab,
             const float* __restrict__ w2g, const float* __restrict__ w3g,
             float* __restrict__ w2R, float* __restrict__ w3R,
             double* __restrict__ totalp)
{
    const int bid = blockIdx.x;
    const int t = threadIdx.x;

    if (bid < K1_BLOCKS) {
        // ---- partial sums of v_src@embs and v_target@embs, 2-way MLP: both
        //      grid-stride elements' loads issue before any compute ----
        float aS[4], aT[4];
#pragma unroll
        for (int i = 0; i < 4; i++) { aS[i] = 0.0f; aT[i] = 0.0f; }

        const float4* emb4 = (const float4*)emb;
        const long long total  = (long long)M_TOTAL * 4;
        const long long stride = (long long)K1_BLOCKS * 256;
        long long f = (long long)bid * 256 + t;

#define RED_CORE(e, sv, tv) { \
        float sq = fmaf(e.x, e.x, fmaf(e.y, e.y, fmaf(e.z, e.z, e.w * e.w))); \
        DPPADDF(sq, QP_XOR1) \
        DPPADDF(sq, QP_XOR2) \
        float invn = 1.0f / sqrtf(sq); \
        float s = (sv) * invn; \
        float tt = (tv) * invn; \
        aS[0] = fmaf(s, e.x, aS[0]);  aS[1] = fmaf(s, e.y, aS[1]); \
        aS[2] = fmaf(s, e.z, aS[2]);  aS[3] = fmaf(s, e.w, aS[3]); \
        aT[0] = fmaf(tt, e.x, aT[0]); aT[1] = fmaf(tt, e.y, aT[1]); \
        aT[2] = fmaf(tt, e.z, aT[2]); aT[3] = fmaf(tt, e.w, aT[3]); }

        for (; f + stride < total; f += 2 * stride) {
            float4 e0 = emb4[f];
            float4 e1 = emb4[f + stride];
            long long r0 = f >> 2, r1 = (f + stride) >> 2;
            float s0 = vsrc[r0], t0 = vtgt[r0];
            float s1 = vsrc[r1], t1 = vtgt[r1];
            RED_CORE(e0, s0, t0)
            RED_CORE(e1, s1, t1)
        }
        if (f < total) {
            float4 e0 = emb4[f];
            long long r0 = f >> 2;
            float s0 = vsrc[r0], t0 = vtgt[r0];
            RED_CORE(e0, s0, t0)
        }
#undef RED_CORE

        double dS[4], dT[4];
#pragma unroll
        for (int i = 0; i < 4; i++) { dS[i] = (double)aS[i]; dT[i] = (double)aT[i]; }
#pragma unroll
        for (int i = 0; i < 4; i++) {
#pragma unroll
            for (int off = 32; off >= 4; off >>= 1) {
                dS[i] += __shfl_down(dS[i], off);
                dT[i] += __shfl_down(dT[i], off);
            }
        }
        __shared__ double lred[4][32];
        int lane = t & 63, wv = t >> 6;
        if (lane < 4) {
#pragma unroll
            for (int i = 0; i < 4; i++) {
                lred[wv][lane * 4 + i]      = dS[i];
                lred[wv][16 + lane * 4 + i] = dT[i];
            }
        }
        __syncthreads();
        if (t < 32) {
            double v = lred[0][t] + lred[1][t] + lred[2][t] + lred[3][t];
            partials[(long long)bid * 32 + t] = v;
        }
    } else if (bid < K1_BLOCKS + 512) {
        // ---- expm(gens[b]) via 16-term Taylor on the 16x16 skew matrix ----
        const int b = bid - K1_BLOCKS;
        const int i = t >> 4, j = t & 15;
        __shared__ float Om[256];
        __shared__ float Ms[256];

        const float* crow = tc + b * 120;
        float o = 0.0f;
        if (i < j)      o = -crow[(i * (31 - i)) / 2 + (j - i - 1)];
        else if (i > j) o =  crow[(j * (31 - j)) / 2 + (i - j - 1)];
        Om[t] = o;
        Ms[t] = o;
        float s = (i == j ? 1.0f : 0.0f) + o;   // S = I + Omega
        __syncthreads();

#pragma unroll
        for (int k = 2; k <= 16; k++) {
            float a0 = 0.0f, a1 = 0.0f, a2 = 0.0f, a3 = 0.0f;
#pragma unroll
            for (int m = 0; m < 4; m++) {
                a0 = fmaf(Om[i * 16 + m],      Ms[m * 16 + j],        a0);
                a1 = fmaf(Om[i * 16 + 4 + m],  Ms[(4 + m) * 16 + j],  a1);
                a2 = fmaf(Om[i * 16 + 8 + m],  Ms[(8 + m) * 16 + j],  a2);
                a3 = fmaf(Om[i * 16 + 12 + m], Ms[(12 + m) * 16 + j], a3);
            }
            float acc = ((a0 + a1) + (a2 + a3)) * (1.0f / (float)k);
            __syncthreads();
            Ms[t] = acc;
            s += acc;
            __syncthreads();
        }
        Rtab[b * 256 + t] = s;
    } else {
        // ---- per-thread-contiguous weight layouts for 512-thread k_steps (R4 layout) ----
        const int b = bid - (K1_BLOCKS + 512);   // 0..515
        if (b == 0 && t == 0) totalp[0] = 0.0;   // zero softmax denominator accumulator
        if (t >= 128) return;
        const int k = t;
        if (b < 512) {
            w3R[b * 128 + k] = w3g[k * 512 + b];
        } else {
            const int p2 = b - 512;     // 0..3
            const int j2 = k;           // 0..127
            for (int m = 0; m < 64; m++)
                w2R[(((p2 << 7) | j2) * 64) + m] = w2g[(64 * p2 + m) * 128 + j2];
        }
    }
}

// -------------------- K2: the sequential 64-step scan (1 block, 512 threads) --------------------
// R4-exact structure (proven 208us): register-resident w2/w3 + readlane broadcasts,
// DPP+ballot argmax, shuffle-free rotation, 3 lgkm-only barriers/step.
extern "C" __global__ __launch_bounds__(512)
__attribute__((amdgpu_waves_per_eu(2, 2)))
void k_steps(const double* __restrict__ partials,
             const float* __restrict__ w1g, const float* __restrict__ b1g,
             const float* __restrict__ b2g, const float* __restrict__ b3g,
             const float* __restrict__ w2R, const float* __restrict__ w3R,
             const float* __restrict__ Rtab, const float* __restrict__ gum,
             const int* __restrict__ nsp,
             float* __restrict__ outL, float* __restrict__ vf_out)
{
    __shared__ __align__(16) float h1s[256];
    __shared__ __align__(16) float h2p[512];
    __shared__ float xs[32];
    __shared__ float b2s[128];
    __shared__ uint2 kidx[8];
    __shared__ double dred[512];

    const int t = threadIdx.x;
    const int lane = t & 63;
    const int wv = t >> 6;
    const int j2 = t & 127, p2 = t >> 7;
    const int c1 = t & 255;           // L1 output column (threads 256-511 shadow 0-255)

    // ---- register-resident weights via volatile one-time loads ----
    const volatile float* w3v = (const volatile float*)(w3R + (size_t)t * 128);
    const volatile float* w2v = (const volatile float*)(w2R + (size_t)t * 64);
#define W3D(c) float4 w3_##c; VLD4(w3_##c, w3v, c)
    REP16(W3D) REP16B(W3D)
#undef W3D
#define W2D(c) float4 w2_##c; VLD4(w2_##c, w2v, c)
    REP16(W2D)
#undef W2D
    const float b3r = b3g[t];

    // w1 v-half columns in registers (16 floats, static indexing only)
    float w1r[16];
    {
        const volatile float* w1v = (const volatile float*)w1g;
#pragma unroll
        for (int m = 0; m < 16; m++) w1r[m] = w1v[m * 256 + c1];
    }
    if (t < 128) b2s[t] = b2g[t];

    // warm Rtab (512 KB) into this XCD's L2 so per-step rotation loads hit L2 not HBM
    float warm = 0.0f;
    for (int i = t; i < 512 * 256 / 4; i += 512) {
        float4 rv = ((const float4*)Rtab)[i];
        warm += (rv.x + rv.y) + (rv.z + rv.w);
    }

    // stage-2 reduce of K1 partials, coalesced: flat[f] has column f%32
    {
        double v = 0.0;
#pragma unroll 4
        for (int i = 0; i < (K1_BLOCKS * 32) / 512; i++) v += partials[i * 512 + t];
        dred[t] = v;
    }

    int ns = nsp[0];
    if (ns > 64) ns = 64;
    if (ns < 0)  ns = 0;
    if (ns == -2147483647) vf_out[0] = warm;   // never true; defeats DCE

    __syncthreads();
    if (t < 32) {
        double s = 0.0;
#pragma unroll
        for (int j = 0; j < 16; j++) s += dred[t + 32 * j];
        xs[t] = (float)s;                      // xs[0:16]=v_cur, xs[16:32]=v_tgt
    }
    __syncthreads();

    // b1_eff = b1 + v_tgt @ w1[16:32]; v replicated per-wave (waves 0-3 only)
    float b1e = 0.0f, vreg = 0.0f;
    if (t < 256) {
        float a = b1g[c1];
#pragma unroll
        for (int m = 0; m < 16; m++)
            a = fmaf(xs[16 + m], w1g[(16 + m) * 256 + c1], a);
        b1e = a;
        vreg = xs[lane & 15];        // lane l holds v[l&15]
    }

    if (ns == 0 && t < 16) vf_out[t] = xs[t];

    for (int step = 0; step < ns; step++) {
        float gv = gum[step * 512 + t];       // hoisted global load (needed at argmax)

        // ---- layer 1: h1 = relu(v @ w1[0:16] + b1_eff); waves 0-3, v in own-wave regs ----
        if (t < 256) {
            float a0 = 0.0f, a1 = 0.0f;
#pragma unroll
            for (int m = 0; m < 8; m++) {
                a0 = fmaf(rlf(vreg, m),     w1r[m],     a0);
                a1 = fmaf(rlf(vreg, 8 + m), w1r[8 + m], a1);
            }
            h1s[t] = fmaxf((a0 + a1) + b1e, 0.0f);
        }
        bar_lds();

        // ---- layer 2 partials: 128 outputs x 4-way K split ----
        {
            float h1seg = h1s[(p2 << 6) | lane];
            float a0 = 0.0f, a1 = 0.0f, a2 = 0.0f, a3 = 0.0f;
#define L2C(c) { a0 = fmaf(rlf(h1seg, 4*(c)+0), w2_##c.x, a0); \
                 a1 = fmaf(rlf(h1seg, 4*(c)+1), w2_##c.y, a1); \
                 a2 = fmaf(rlf(h1seg, 4*(c)+2), w2_##c.z, a2); \
                 a3 = fmaf(rlf(h1seg, 4*(c)+3), w2_##c.w, a3); }
            REP16(L2C)
#undef L2C
            h2p[(p2 << 7) | j2] = (a0 + a1) + (a2 + a3);
        }
        bar_lds();

        // ---- layer 3: reconstruct h2 in-lane (fused reduce), then logits ----
        float lg;
        {
            float h2lo = fmaxf(((h2p[lane] + h2p[128 + lane]) +
                                (h2p[256 + lane] + h2p[384 + lane])) + b2s[lane], 0.0f);
            float h2hi = fmaxf(((h2p[64 + lane] + h2p[192 + lane]) +
                                (h2p[320 + lane] + h2p[448 + lane])) + b2s[64 + lane], 0.0f);
            float lg0 = 0.0f, lg1 = 0.0f, lg2 = 0.0f, lg3 = 0.0f;
#define L3LO(c) { lg0 = fmaf(rlf(h2lo, 4*(c)+0), w3_##c.x, lg0); \
                  lg1 = fmaf(rlf(h2lo, 4*(c)+1), w3_##c.y, lg1); \
                  lg2 = fmaf(rlf(h2lo, 4*(c)+2), w3_##c.z, lg2); \
                  lg3 = fmaf(rlf(h2lo, 4*(c)+3), w3_##c.w, lg3); }
#define L3HI(c) { lg0 = fmaf(rlf(h2hi, 4*(c)-64), w3_##c.x, lg0); \
                  lg1 = fmaf(rlf(h2hi, 4*(c)-63), w3_##c.y, lg1); \
                  lg2 = fmaf(rlf(h2hi, 4*(c)-62), w3_##c.z, lg2); \
                  lg3 = fmaf(rlf(h2hi, 4*(c)-61), w3_##c.w, lg3); }
            REP16(L3LO) REP16B(L3HI)
#undef L3LO
#undef L3HI
            lg = ((lg0 + lg1) + (lg2 + lg3)) + b3r;
        }
        outL[step * 512 + t] = lg;   // fire-and-forget; lgkm barriers don't drain vmcnt

        // ---- argmax(logits + gumbel): DPP wave-max + ballot (no bpermute chain) ----
        {
            unsigned ok = orderf(lg + gv);
            unsigned m = ok;
            DPPMAXU(m, 0x111)   // row_shr:1
            DPPMAXU(m, 0x112)   // row_shr:2
            DPPMAXU(m, 0x114)   // row_shr:4
            DPPMAXU(m, 0x118)   // row_shr:8  -> lane15 of each row has row max
            DPPMAXU(m, 0x142)   // row_bcast15
            DPPMAXU(m, 0x143)   // row_bcast31 -> lane63 has wave max
            unsigned wmax = (unsigned)__builtin_amdgcn_readlane((int)m, 63);
            unsigned long long mask = __ballot(ok == wmax);
            if (lane == 0) {
                uint2 kv; kv.x = wmax; kv.y = (unsigned)(wv * 64 + (__ffsll(mask) - 1));
                kidx[wv] = kv;
            }
        }
        bar_lds();

        // ---- rotation: waves 0-3, lanes 0-15; v' = normalize(R[bi] @ v), no shuffles ----
        if (t < 256 && lane < 16) {
            uint2 K0, K1, K2, K3, K4, K5, K6, K7;
            { uint4 a = *(const uint4*)&kidx[0]; K0.x=a.x; K0.y=a.y; K1.x=a.z; K1.y=a.w; }
            { uint4 a = *(const uint4*)&kidx[2]; K2.x=a.x; K2.y=a.y; K3.x=a.z; K3.y=a.w; }
            { uint4 a = *(const uint4*)&kidx[4]; K4.x=a.x; K4.y=a.y; K5.x=a.z; K5.y=a.w; }
            { uint4 a = *(const uint4*)&kidx[6]; K6.x=a.x; K6.y=a.y; K7.x=a.z; K7.y=a.w; }
            uint2 w01 = pick2(K0, K1), w23 = pick2(K2, K3);
            uint2 w45 = pick2(K4, K5), w67 = pick2(K6, K7);
            uint2 win = pick2(pick2(w01, w23), pick2(w45, w67));
            const int bi = (int)win.y;

            const float4* rp = (const float4*)(Rtab + (size_t)bi * 256 + lane * 16);
            float4 ra = rp[0], rb = rp[1], rc = rp[2], rd = rp[3];
            // 4 independent chains, then tree-sum
            float p0 = ra.x * rlf(vreg, 0);
            float p1 = rb.x * rlf(vreg, 4);
            float p2r = rc.x * rlf(vreg, 8);
            float p3 = rd.x * rlf(vreg, 12);
            p0 = fmaf(ra.y, rlf(vreg, 1), p0);
            p1 = fmaf(rb.y, rlf(vreg, 5), p1);
            p2r = fmaf(rc.y, rlf(vreg, 9), p2r);
            p3 = fmaf(rd.y, rlf(vreg, 13), p3);
            p0 = fmaf(ra.z, rlf(vreg, 2), p0);
            p1 = fmaf(rb.z, rlf(vreg, 6), p1);
            p2r = fmaf(rc.z, rlf(vreg, 10), p2r);
            p3 = fmaf(rd.z, rlf(vreg, 14), p3);
            p0 = fmaf(ra.w, rlf(vreg, 3), p0);
            p1 = fmaf(rb.w, rlf(vreg, 7), p1);
            p2r = fmaf(rc.w, rlf(vreg, 11), p2r);
            p3 = fmaf(rd.w, rlf(vreg, 15), p3);
            float pr = (p0 + p1) + (p2r + p3);

            float s2 = pr * pr;                 // sum over lanes 0-15 via DPP row-shr
            DPPADDF(s2, 0x111)
            DPPADDF(s2, 0x112)
            DPPADDF(s2, 0x114)
            DPPADDF(s2, 0x118)                  // lane15 = full row sum
            float n2 = rlf(s2, 15);
            float invn = 1.0f / sqrtf(n2);
            vreg = pr * invn;                   // lane l holds v'[l], waves 0-3 consistent
            if (step == ns - 1 && t < 16) vf_out[t] = vreg;
        }
        // no barrier here: next L1 uses only own-wave registers; h1s writes are
        // separated from this step's readers by the barriers above.
    }
}

// -------------------- K3: scores = exp(dot(v_fin, emb_row_norm)); 2-way MLP; block sums -> atomic total --------------------
extern "C" __global__ __launch_bounds__(256)
void k_scores(const float* __restrict__ emb, const float* __restrict__ vf16,
              float* __restrict__ outP, double* __restrict__ totalp)
{
    __shared__ float vfs[16];
    const int tid = threadIdx.x;
    const int bid = blockIdx.x;
    const int q = tid & 3;
    if (tid < 16) vfs[tid] = vf16[tid];
    __syncthreads();
    float v0 = vfs[q * 4 + 0], v1 = vfs[q * 4 + 1], v2 = vfs[q * 4 + 2], v3 = vfs[q * 4 + 3];

    const float4* emb4 = (const float4*)emb;
    const long long total  = (long long)M_TOTAL * 4;
    const long long stride = (long long)K3_BLOCKS * 256;
    long long f = (long long)bid * 256 + tid;
    double bsum = 0.0;

#define SC_CORE(e, rr) { \
        float sq = fmaf(e.x, e.x, fmaf(e.y, e.y, fmaf(e.z, e.z, e.w * e.w))); \
        float d  = fmaf(e.x, v0, fmaf(e.y, v1, fmaf(e.z, v2, e.w * v3))); \
        DPPADDF(sq, QP_XOR1) \
        DPPADDF(d,  QP_XOR1) \
        DPPADDF(sq, QP_XOR2) \
        DPPADDF(d,  QP_XOR2) \
        float ex = expf(d / sqrtf(sq)); \
        if (q == 0) { outP[rr] = ex; bsum += (double)ex; } }

    for (; f + stride < total; f += 2 * stride) {
        float4 e0 = emb4[f];
        float4 e1 = emb4[f + stride];
        long long r0 = f >> 2, r1 = (f + stride) >> 2;
        SC_CORE(e0, r0)
        SC_CORE(e1, r1)
    }
    if (f < total) {
        float4 e0 = emb4[f];
        long long r0 = f >> 2;
        SC_CORE(e0, r0)
    }
#undef SC_CORE

#pragma unroll
    for (int off = 4; off <= 32; off <<= 1) bsum += __shfl_down(bsum, off);
    __shared__ double lred[4];
    if ((tid & 63) == 0) lred[tid >> 6] = bsum;
    __syncthreads();
    if (tid == 0) atomicAdd(totalp, lred[0] + lred[1] + lred[2] + lred[3]);
}

// -------------------- K5: normalize --------------------
extern "C" __global__ __launch_bounds__(256)
void k_scale(float* __restrict__ outP, const double* __restrict__ totalp)
{
    const float inv = 1.0f / (float)totalp[0];
    long long r4 = (long long)blockIdx.x * 256 + threadIdx.x;
    if (r4 < M_TOTAL / 4) {
        float4* p = (float4*)outP;
        float4 v = p[r4];
        v.x *= inv; v.y *= inv; v.z *= inv; v.w *= inv;
        p[r4] = v;
    }
}

extern "C" void kernel_launch(void* const* d_in, const int* in_sizes, int n_in,
                              void* d_out, int out_size, void* d_ws, size_t ws_size,
                              hipStream_t stream)
{
    const float* vsrc = (const float*)d_in[0];
    const float* vtgt = (const float*)d_in[1];
    const float* emb  = (const float*)d_in[2];
    const float* tc   = (const float*)d_in[3];
    // d_in[4] = bases: structure is hard-coded (omega[i][j] = -/+ coeffs[t*, k(i,j)])
    const float* w1 = (const float*)d_in[5];
    const float* b1 = (const float*)d_in[6];
    const float* w2 = (const float*)d_in[7];
    const float* b2 = (const float*)d_in[8];
    const float* w3 = (const float*)d_in[9];
    const float* b3 = (const float*)d_in[10];
    const float* gum = (const float*)d_in[11];
    const int* nsp   = (const int*)d_in[12];

    float* outP = (float*)d_out;          // pred_marking [2M]
    float* outL = outP + M_TOTAL;         // logits [64*512]

    double* wsd      = (double*)d_ws;
    double* partials = wsd;                         // 1024*32 doubles (region sized for 2048*32)
    double* totalp   = wsd + 2048 * 32;             // 1 double
    float*  vf       = (float*)(totalp + 1);        // 16 floats

    // Scratch tables live in the pred_marking output region; fully consumed by
    // k_steps before k_scores/k_scale overwrite outP.
    float* Rtab = outP;                   // 512*256 = 131072 floats
    float* w3R  = outP + 131072;          // 512*128 =  65536 floats
    float* w2R  = outP + 196608;          // 512*64  =  32768 floats

    // Fused front: reduce (1024 blocks) + expm (512) + weight relayout (516)
    k_front<<<K1_BLOCKS + 512 + 516, 256, 0, stream>>>(emb, vsrc, vtgt, partials,
                                                       tc, Rtab, w2, w3, w2R, w3R, totalp);
    k_steps<<<1, 512, 0, stream>>>(partials, w1, b1, b2, b3, w2R, w3R, Rtab, gum, nsp, outL, vf);
    k_scores<<<K3_BLOCKS, 256, 0, stream>>>(emb, vf, outP, totalp);
    k_scale<<<(M_TOTAL / 4 + 255) / 256, 256, 0, stream>>>(outP, totalp);
}

// Round 10
// 463.146 us; speedup vs baseline: 1.0066x; 1.0066x over previous
//
#include <hip/hip_runtime.h>

#define M_TOTAL   2000000
#define NT        512
#define K1_BLOCKS 1024
#define K3_BLOCKS 2048

__device__ __forceinline__ float rlf(float v, int l) {
    union { float f; int i; } u; u.f = v;
    u.i = __builtin_amdgcn_readlane(u.i, l);
    return u.f;
}

// Barrier with LDS-only drain: in-loop cross-thread data is exclusively LDS,
// so vmcnt (global outL stores / gum / Rtab loads) never needs draining.
__device__ __forceinline__ void bar_lds() {
    asm volatile("s_waitcnt lgkmcnt(0)" ::: "memory");
    __builtin_amdgcn_s_barrier();
    asm volatile("" ::: "memory");
}

// DPP helpers (register-crossbar cross-lane, ~4cy vs ~100cy for ds_bpermute shuffles).
#define DPPMAXU(m, ctrl) { unsigned _d = (unsigned)__builtin_amdgcn_update_dpp(0, (int)(m), (ctrl), 0xF, 0xF, true); \
                           if (_d > (m)) (m) = _d; }
#define DPPADDF(s, ctrl) { float _d = __int_as_float(__builtin_amdgcn_update_dpp(0, __float_as_int(s), (ctrl), 0xF, 0xF, true)); \
                           (s) += _d; }
// quad_perm controls: xor1 = [1,0,3,2] = 0xB1 ; xor2 = [2,3,0,1] = 0x4E
#define QP_XOR1 0xB1
#define QP_XOR2 0x4E

__device__ __forceinline__ unsigned orderf(float f) {
    unsigned u = __float_as_uint(f);
    return u ^ (((unsigned)((int)u >> 31)) | 0x80000000u);   // monotone float->uint
}

__device__ __forceinline__ uint2 pick2(uint2 a, uint2 b) {
    // larger key wins; equal key -> smaller index (first-index tiebreak)
    bool takeb = (b.x > a.x) || (b.x == a.x && b.y < a.y);
    return takeb ? b : a;
}

#define REP16(M)  M(0) M(1) M(2) M(3) M(4) M(5) M(6) M(7) M(8) M(9) M(10) M(11) M(12) M(13) M(14) M(15)
#define REP16B(M) M(16) M(17) M(18) M(19) M(20) M(21) M(22) M(23) M(24) M(25) M(26) M(27) M(28) M(29) M(30) M(31)

// Volatile load of 4 consecutive floats: performed exactly once, where written.
#define VLD4(dst, base, c) { const volatile float* _p = (base) + 4*(c); \
    dst.x = _p[0]; dst.y = _p[1]; dst.z = _p[2]; dst.w = _p[3]; }

// -------------------- K_front: fused reduce (blocks 0..1023) + expm (1024..1535) + relayout (1536..2051) --------------------
extern "C" __global__ __launch_bounds__(256)
void k_front(const float* __restrict__ emb, const float* __restrict__ vsrc,
             const float* __restrict__ vtgt, double* __restrict__ partials,
             const float* __restrict__ tc, float* __restrict__ Rtab,
             const float* __restrict__ w2g, const float* __restrict__ w3g,
             float* __restrict__ w2R, float* __restrict__ w3R,
             double* __restrict__ totalp)
{
    const int bid = blockIdx.x;
    const int t = threadIdx.x;

    if (bid < K1_BLOCKS) {
        // ---- partial sums of v_src@embs and v_target@embs (coalesced, f32 accum:
        //      only ~31 terms/accumulator so f32 is exact to ~1e-6) ----
        float aS[4], aT[4];
#pragma unroll
        for (int i = 0; i < 4; i++) { aS[i] = 0.0f; aT[i] = 0.0f; }

        const float4* emb4 = (const float4*)emb;
        for (long long f = (long long)bid * 256 + t; f < (long long)M_TOTAL * 4;
             f += (long long)K1_BLOCKS * 256) {
            float4 e = emb4[f];
            long long r = f >> 2;
            float sq = fmaf(e.x, e.x, fmaf(e.y, e.y, fmaf(e.z, e.z, e.w * e.w)));
            DPPADDF(sq, QP_XOR1)
            DPPADDF(sq, QP_XOR2)
            float invn = 1.0f / sqrtf(sq);
            float s = vsrc[r] * invn;
            float tv = vtgt[r] * invn;
            aS[0] = fmaf(s, e.x, aS[0]);  aS[1] = fmaf(s, e.y, aS[1]);
            aS[2] = fmaf(s, e.z, aS[2]);  aS[3] = fmaf(s, e.w, aS[3]);
            aT[0] = fmaf(tv, e.x, aT[0]); aT[1] = fmaf(tv, e.y, aT[1]);
            aT[2] = fmaf(tv, e.z, aT[2]); aT[3] = fmaf(tv, e.w, aT[3]);
        }
        double dS[4], dT[4];
#pragma unroll
        for (int i = 0; i < 4; i++) { dS[i] = (double)aS[i]; dT[i] = (double)aT[i]; }
#pragma unroll
        for (int i = 0; i < 4; i++) {
#pragma unroll
            for (int off = 32; off >= 4; off >>= 1) {
                dS[i] += __shfl_down(dS[i], off);
                dT[i] += __shfl_down(dT[i], off);
            }
        }
        __shared__ double lred[4][32];
        int lane = t & 63, wv = t >> 6;
        if (lane < 4) {
#pragma unroll
            for (int i = 0; i < 4; i++) {
                lred[wv][lane * 4 + i]      = dS[i];
                lred[wv][16 + lane * 4 + i] = dT[i];
            }
        }
        __syncthreads();
        if (t < 32) {
            double v = lred[0][t] + lred[1][t] + lred[2][t] + lred[3][t];
            partials[(long long)bid * 32 + t] = v;
        }
    } else if (bid < K1_BLOCKS + 512) {
        // ---- expm(gens[b]) via 16-term Taylor on the 16x16 skew matrix ----
        const int b = bid - K1_BLOCKS;
        const int i = t >> 4, j = t & 15;
        __shared__ float Om[256];
        __shared__ float Ms[256];

        const float* crow = tc + b * 120;
        float o = 0.0f;
        if (i < j)      o = -crow[(i * (31 - i)) / 2 + (j - i - 1)];
        else if (i > j) o =  crow[(j * (31 - j)) / 2 + (i - j - 1)];
        Om[t] = o;
        Ms[t] = o;
        float s = (i == j ? 1.0f : 0.0f) + o;   // S = I + Omega
        __syncthreads();

#pragma unroll
        for (int k = 2; k <= 16; k++) {
            float a0 = 0.0f, a1 = 0.0f, a2 = 0.0f, a3 = 0.0f;
#pragma unroll
            for (int m = 0; m < 4; m++) {
                a0 = fmaf(Om[i * 16 + m],      Ms[m * 16 + j],        a0);
                a1 = fmaf(Om[i * 16 + 4 + m],  Ms[(4 + m) * 16 + j],  a1);
                a2 = fmaf(Om[i * 16 + 8 + m],  Ms[(8 + m) * 16 + j],  a2);
                a3 = fmaf(Om[i * 16 + 12 + m], Ms[(12 + m) * 16 + j], a3);
            }
            float acc = ((a0 + a1) + (a2 + a3)) * (1.0f / (float)k);
            __syncthreads();
            Ms[t] = acc;
            s += acc;
            __syncthreads();
        }
        Rtab[b * 256 + t] = s;
    } else {
        // ---- per-thread-contiguous weight layouts for 512-thread k_steps (R4 layout) ----
        const int b = bid - (K1_BLOCKS + 512);   // 0..515
        if (b == 0 && t == 0) totalp[0] = 0.0;   // zero softmax denominator accumulator
        if (t >= 128) return;
        const int k = t;
        if (b < 512) {
            w3R[b * 128 + k] = w3g[k * 512 + b];
        } else {
            const int p2 = b - 512;     // 0..3
            const int j2 = k;           // 0..127
            for (int m = 0; m < 64; m++)
                w2R[(((p2 << 7) | j2) * 64) + m] = w2g[(64 * p2 + m) * 128 + j2];
        }
    }
}

// -------------------- K2: the sequential 64-step scan (1 block, 512 threads) --------------------
// R8 structure with 8-deep readlane batching: each group of 8 v_readlane results is
// materialized in named temporaries BEFORE its 8 fmas, so the scheduler can hide the
// SALU->VALU (SGPR write->read) dependency instead of stalling per pair.
extern "C" __global__ __launch_bounds__(512)
__attribute__((amdgpu_waves_per_eu(2, 2)))
void k_steps(const double* __restrict__ partials,
             const float* __restrict__ w1g, const float* __restrict__ b1g,
             const float* __restrict__ b2g, const float* __restrict__ b3g,
             const float* __restrict__ w2R, const float* __restrict__ w3R,
             const float* __restrict__ Rtab, const float* __restrict__ gum,
             const int* __restrict__ nsp,
             float* __restrict__ outL, float* __restrict__ vf_out)
{
    __shared__ __align__(16) float h1s[256];
    __shared__ __align__(16) float h2p[512];
    __shared__ float xs[32];
    __shared__ float b2s[128];
    __shared__ uint2 kidx[8];
    __shared__ double dred[512];

    const int t = threadIdx.x;
    const int lane = t & 63;
    const int wv = t >> 6;
    const int j2 = t & 127, p2 = t >> 7;
    const int c1 = t & 255;           // L1 output column (threads 256-511 shadow 0-255)

    // ---- register-resident weights via volatile one-time loads ----
    const volatile float* w3v = (const volatile float*)(w3R + (size_t)t * 128);
    const volatile float* w2v = (const volatile float*)(w2R + (size_t)t * 64);
#define W3D(c) float4 w3_##c; VLD4(w3_##c, w3v, c)
    REP16(W3D) REP16B(W3D)
#undef W3D
#define W2D(c) float4 w2_##c; VLD4(w2_##c, w2v, c)
    REP16(W2D)
#undef W2D
    const float b3r = b3g[t];

    // w1 v-half columns in registers (16 floats, static indexing only)
    float w1r[16];
    {
        const volatile float* w1v = (const volatile float*)w1g;
#pragma unroll
        for (int m = 0; m < 16; m++) w1r[m] = w1v[m * 256 + c1];
    }
    if (t < 128) b2s[t] = b2g[t];

    // warm Rtab (512 KB) into this XCD's L2 so per-step rotation loads hit L2 not HBM
    float warm = 0.0f;
    for (int i = t; i < 512 * 256 / 4; i += 512) {
        float4 rv = ((const float4*)Rtab)[i];
        warm += (rv.x + rv.y) + (rv.z + rv.w);
    }

    // stage-2 reduce of K1 partials, coalesced: flat[f] has column f%32
    {
        double v = 0.0;
#pragma unroll 4
        for (int i = 0; i < (K1_BLOCKS * 32) / 512; i++) v += partials[i * 512 + t];
        dred[t] = v;
    }

    int ns = nsp[0];
    if (ns > 64) ns = 64;
    if (ns < 0)  ns = 0;
    if (ns == -2147483647) vf_out[0] = warm;   // never true; defeats DCE

    __syncthreads();
    if (t < 32) {
        double s = 0.0;
#pragma unroll
        for (int j = 0; j < 16; j++) s += dred[t + 32 * j];
        xs[t] = (float)s;                      // xs[0:16]=v_cur, xs[16:32]=v_tgt
    }
    __syncthreads();

    // b1_eff = b1 + v_tgt @ w1[16:32]; v replicated per-wave (waves 0-3 only)
    float b1e = 0.0f, vreg = 0.0f;
    if (t < 256) {
        float a = b1g[c1];
#pragma unroll
        for (int m = 0; m < 16; m++)
            a = fmaf(xs[16 + m], w1g[(16 + m) * 256 + c1], a);
        b1e = a;
        vreg = xs[lane & 15];        // lane l holds v[l&15]
    }

    if (ns == 0 && t < 16) vf_out[t] = xs[t];

    for (int step = 0; step < ns; step++) {
        float gv = gum[step * 512 + t];       // hoisted global load (needed at argmax)

        // ---- layer 1: h1 = relu(v @ w1[0:16] + b1_eff); waves 0-3, batch-8 readlanes ----
        if (t < 256) {
            float m0 = rlf(vreg, 0),  m1 = rlf(vreg, 1),  m2 = rlf(vreg, 2),  m3 = rlf(vreg, 3);
            float m4 = rlf(vreg, 4),  m5 = rlf(vreg, 5),  m6 = rlf(vreg, 6),  m7 = rlf(vreg, 7);
            float a0 = fmaf(m0, w1r[0], 0.0f), a1 = fmaf(m1, w1r[1], 0.0f);
            a0 = fmaf(m2, w1r[2], a0); a1 = fmaf(m3, w1r[3], a1);
            a0 = fmaf(m4, w1r[4], a0); a1 = fmaf(m5, w1r[5], a1);
            a0 = fmaf(m6, w1r[6], a0); a1 = fmaf(m7, w1r[7], a1);
            float n0 = rlf(vreg, 8),  n1 = rlf(vreg, 9),  n2 = rlf(vreg, 10), n3 = rlf(vreg, 11);
            float n4 = rlf(vreg, 12), n5 = rlf(vreg, 13), n6 = rlf(vreg, 14), n7 = rlf(vreg, 15);
            a0 = fmaf(n0, w1r[8],  a0); a1 = fmaf(n1, w1r[9],  a1);
            a0 = fmaf(n2, w1r[10], a0); a1 = fmaf(n3, w1r[11], a1);
            a0 = fmaf(n4, w1r[12], a0); a1 = fmaf(n5, w1r[13], a1);
            a0 = fmaf(n6, w1r[14], a0); a1 = fmaf(n7, w1r[15], a1);
            h1s[t] = fmaxf((a0 + a1) + b1e, 0.0f);
        }
        bar_lds();

        // ---- layer 2 partials: 128 outputs x 4-way K split; batch-8 readlanes ----
        {
            float h1seg = h1s[(p2 << 6) | lane];
            float a0 = 0.0f, a1 = 0.0f, a2 = 0.0f, a3 = 0.0f;
#define L2B(c0, c1c) { \
            float m0 = rlf(h1seg, 4*(c0)+0),  m1 = rlf(h1seg, 4*(c0)+1); \
            float m2 = rlf(h1seg, 4*(c0)+2),  m3 = rlf(h1seg, 4*(c0)+3); \
            float m4 = rlf(h1seg, 4*(c1c)+0), m5 = rlf(h1seg, 4*(c1c)+1); \
            float m6 = rlf(h1seg, 4*(c1c)+2), m7 = rlf(h1seg, 4*(c1c)+3); \
            a0 = fmaf(m0, w2_##c0.x, a0);  a1 = fmaf(m1, w2_##c0.y, a1); \
            a2 = fmaf(m2, w2_##c0.z, a2);  a3 = fmaf(m3, w2_##c0.w, a3); \
            a0 = fmaf(m4, w2_##c1c.x, a0); a1 = fmaf(m5, w2_##c1c.y, a1); \
            a2 = fmaf(m6, w2_##c1c.z, a2); a3 = fmaf(m7, w2_##c1c.w, a3); }
            L2B(0, 1)  L2B(2, 3)  L2B(4, 5)  L2B(6, 7)
            L2B(8, 9)  L2B(10, 11) L2B(12, 13) L2B(14, 15)
#undef L2B
            h2p[(p2 << 7) | j2] = (a0 + a1) + (a2 + a3);
        }
        bar_lds();

        // ---- layer 3: reconstruct h2 in-lane (fused reduce), then logits; batch-8 readlanes ----
        float lg;
        {
            float h2lo = fmaxf(((h2p[lane] + h2p[128 + lane]) +
                                (h2p[256 + lane] + h2p[384 + lane])) + b2s[lane], 0.0f);
            float h2hi = fmaxf(((h2p[64 + lane] + h2p[192 + lane]) +
                                (h2p[320 + lane] + h2p[448 + lane])) + b2s[64 + lane], 0.0f);
            float lg0 = 0.0f, lg1 = 0.0f, lg2 = 0.0f, lg3 = 0.0f;
#define L3BLO(c0, c1c) { \
            float m0 = rlf(h2lo, 4*(c0)+0),  m1 = rlf(h2lo, 4*(c0)+1); \
            float m2 = rlf(h2lo, 4*(c0)+2),  m3 = rlf(h2lo, 4*(c0)+3); \
            float m4 = rlf(h2lo, 4*(c1c)+0), m5 = rlf(h2lo, 4*(c1c)+1); \
            float m6 = rlf(h2lo, 4*(c1c)+2), m7 = rlf(h2lo, 4*(c1c)+3); \
            lg0 = fmaf(m0, w3_##c0.x, lg0);  lg1 = fmaf(m1, w3_##c0.y, lg1); \
            lg2 = fmaf(m2, w3_##c0.z, lg2);  lg3 = fmaf(m3, w3_##c0.w, lg3); \
            lg0 = fmaf(m4, w3_##c1c.x, lg0); lg1 = fmaf(m5, w3_##c1c.y, lg1); \
            lg2 = fmaf(m6, w3_##c1c.z, lg2); lg3 = fmaf(m7, w3_##c1c.w, lg3); }
#define L3BHI(c0, c1c) { \
            float m0 = rlf(h2hi, 4*(c0)-64), m1 = rlf(h2hi, 4*(c0)-63); \
            float m2 = rlf(h2hi, 4*(c0)-62), m3 = rlf(h2hi, 4*(c0)-61); \
            float m4 = rlf(h2hi, 4*(c1c)-64), m5 = rlf(h2hi, 4*(c1c)-63); \
            float m6 = rlf(h2hi, 4*(c1c)-62), m7 = rlf(h2hi, 4*(c1c)-61); \
            lg0 = fmaf(m0, w3_##c0.x, lg0);  lg1 = fmaf(m1, w3_##c0.y, lg1); \
            lg2 = fmaf(m2, w3_##c0.z, lg2);  lg3 = fmaf(m3, w3_##c0.w, lg3); \
            lg0 = fmaf(m4, w3_##c1c.x, lg0); lg1 = fmaf(m5, w3_##c1c.y, lg1); \
            lg2 = fmaf(m6, w3_##c1c.z, lg2); lg3 = fmaf(m7, w3_##c1c.w, lg3); }
            L3BLO(0, 1)   L3BLO(2, 3)   L3BLO(4, 5)   L3BLO(6, 7)
            L3BLO(8, 9)   L3BLO(10, 11) L3BLO(12, 13) L3BLO(14, 15)
            L3BHI(16, 17) L3BHI(18, 19) L3BHI(20, 21) L3BHI(22, 23)
            L3BHI(24, 25) L3BHI(26, 27) L3BHI(28, 29) L3BHI(30, 31)
#undef L3BLO
#undef L3BHI
            lg = ((lg0 + lg1) + (lg2 + lg3)) + b3r;
        }
        outL[step * 512 + t] = lg;   // fire-and-forget; lgkm barriers don't drain vmcnt

        // ---- argmax(logits + gumbel): DPP wave-max + ballot (no bpermute chain) ----
        {
            unsigned ok = orderf(lg + gv);
            unsigned m = ok;
            DPPMAXU(m, 0x111)   // row_shr:1
            DPPMAXU(m, 0x112)   // row_shr:2
            DPPMAXU(m, 0x114)   // row_shr:4
            DPPMAXU(m, 0x118)   // row_shr:8  -> lane15 of each row has row max
            DPPMAXU(m, 0x142)   // row_bcast15
            DPPMAXU(m, 0x143)   // row_bcast31 -> lane63 has wave max
            unsigned wmax = (unsigned)__builtin_amdgcn_readlane((int)m, 63);
            unsigned long long mask = __ballot(ok == wmax);
            if (lane == 0) {
                uint2 kv; kv.x = wmax; kv.y = (unsigned)(wv * 64 + (__ffsll(mask) - 1));
                kidx[wv] = kv;
            }
        }
        bar_lds();

        // ---- rotation: waves 0-3, lanes 0-15; v' = normalize(R[bi] @ v), no shuffles ----
        if (t < 256 && lane < 16) {
            uint2 K0, K1, K2, K3, K4, K5, K6, K7;
            { uint4 a = *(const uint4*)&kidx[0]; K0.x=a.x; K0.y=a.y; K1.x=a.z; K1.y=a.w; }
            { uint4 a = *(const uint4*)&kidx[2]; K2.x=a.x; K2.y=a.y; K3.x=a.z; K3.y=a.w; }
            { uint4 a = *(const uint4*)&kidx[4]; K4.x=a.x; K4.y=a.y; K5.x=a.z; K5.y=a.w; }
            { uint4 a = *(const uint4*)&kidx[6]; K6.x=a.x; K6.y=a.y; K7.x=a.z; K7.y=a.w; }
            uint2 w01 = pick2(K0, K1), w23 = pick2(K2, K3);
            uint2 w45 = pick2(K4, K5), w67 = pick2(K6, K7);
            uint2 win = pick2(pick2(w01, w23), pick2(w45, w67));
            const int bi = (int)win.y;

            const float4* rp = (const float4*)(Rtab + (size_t)bi * 256 + lane * 16);
            float4 ra = rp[0], rb = rp[1], rc = rp[2], rd = rp[3];
            // batch-16 readlanes, then 4 independent fma chains, tree-sum
            float v0r = rlf(vreg, 0),  v1r = rlf(vreg, 1),  v2r = rlf(vreg, 2),  v3r = rlf(vreg, 3);
            float v4r = rlf(vreg, 4),  v5r = rlf(vreg, 5),  v6r = rlf(vreg, 6),  v7r = rlf(vreg, 7);
            float v8r = rlf(vreg, 8),  v9r = rlf(vreg, 9),  vAr = rlf(vreg, 10), vBr = rlf(vreg, 11);
            float vCr = rlf(vreg, 12), vDr = rlf(vreg, 13), vEr = rlf(vreg, 14), vFr = rlf(vreg, 15);
            float p0 = ra.x * v0r;
            float p1 = rb.x * v4r;
            float p2r = rc.x * v8r;
            float p3 = rd.x * vCr;
            p0 = fmaf(ra.y, v1r, p0);
            p1 = fmaf(rb.y, v5r, p1);
            p2r = fmaf(rc.y, v9r, p2r);
            p3 = fmaf(rd.y, vDr, p3);
            p0 = fmaf(ra.z, v2r, p0);
            p1 = fmaf(rb.z, v6r, p1);
            p2r = fmaf(rc.z, vAr, p2r);
            p3 = fmaf(rd.z, vEr, p3);
            p0 = fmaf(ra.w, v3r, p0);
            p1 = fmaf(rb.w, v7r, p1);
            p2r = fmaf(rc.w, vBr, p2r);
            p3 = fmaf(rd.w, vFr, p3);
            float pr = (p0 + p1) + (p2r + p3);

            float s2 = pr * pr;                 // sum over lanes 0-15 via DPP row-shr
            DPPADDF(s2, 0x111)
            DPPADDF(s2, 0x112)
            DPPADDF(s2, 0x114)
            DPPADDF(s2, 0x118)                  // lane15 = full row sum
            float n2 = rlf(s2, 15);
            float invn = 1.0f / sqrtf(n2);
            vreg = pr * invn;                   // lane l holds v'[l], waves 0-3 consistent
            if (step == ns - 1 && t < 16) vf_out[t] = vreg;
        }
        // no barrier here: next L1 uses only own-wave registers; h1s writes are
        // separated from this step's readers by the barriers above.
    }
}

// -------------------- K3: scores = exp(dot(v_fin, emb_row_norm)); block sums -> atomic total --------------------
extern "C" __global__ __launch_bounds__(256)
void k_scores(const float* __restrict__ emb, const float* __restrict__ vf16,
              float* __restrict__ outP, double* __restrict__ totalp)
{
    __shared__ float vfs[16];
    const int tid = threadIdx.x;
    const int bid = blockIdx.x;
    const int q = tid & 3;
    if (tid < 16) vfs[tid] = vf16[tid];
    __syncthreads();
    float v0 = vfs[q * 4 + 0], v1 = vfs[q * 4 + 1], v2 = vfs[q * 4 + 2], v3 = vfs[q * 4 + 3];

    const float4* emb4 = (const float4*)emb;
    double bsum = 0.0;
    for (long long f = (long long)bid * 256 + tid; f < (long long)M_TOTAL * 4;
         f += (long long)K3_BLOCKS * 256) {
        float4 e = emb4[f];
        long long r = f >> 2;
        float sq = fmaf(e.x, e.x, fmaf(e.y, e.y, fmaf(e.z, e.z, e.w * e.w)));
        float d  = fmaf(e.x, v0, fmaf(e.y, v1, fmaf(e.z, v2, e.w * v3)));
        DPPADDF(sq, QP_XOR1)
        DPPADDF(d,  QP_XOR1)
        DPPADDF(sq, QP_XOR2)
        DPPADDF(d,  QP_XOR2)
        float ex = expf(d / sqrtf(sq));   // |score| <= 1, no overflow; softmax shift cancels
        if (q == 0) {
            outP[r] = ex;
            bsum += (double)ex;
        }
    }
#pragma unroll
    for (int off = 4; off <= 32; off <<= 1) bsum += __shfl_down(bsum, off);
    __shared__ double lred[4];
    if ((tid & 63) == 0) lred[tid >> 6] = bsum;
    __syncthreads();
    if (tid == 0) atomicAdd(totalp, lred[0] + lred[1] + lred[2] + lred[3]);
}

// -------------------- K5: normalize --------------------
extern "C" __global__ __launch_bounds__(256)
void k_scale(float* __restrict__ outP, const double* __restrict__ totalp)
{
    const float inv = 1.0f / (float)totalp[0];
    long long r4 = (long long)blockIdx.x * 256 + threadIdx.x;
    if (r4 < M_TOTAL / 4) {
        float4* p = (float4*)outP;
        float4 v = p[r4];
        v.x *= inv; v.y *= inv; v.z *= inv; v.w *= inv;
        p[r4] = v;
    }
}

extern "C" void kernel_launch(void* const* d_in, const int* in_sizes, int n_in,
                              void* d_out, int out_size, void* d_ws, size_t ws_size,
                              hipStream_t stream)
{
    const float* vsrc = (const float*)d_in[0];
    const float* vtgt = (const float*)d_in[1];
    const float* emb  = (const float*)d_in[2];
    const float* tc   = (const float*)d_in[3];
    // d_in[4] = bases: structure is hard-coded (omega[i][j] = -/+ coeffs[t*, k(i,j)])
    const float* w1 = (const float*)d_in[5];
    const float* b1 = (const float*)d_in[6];
    const float* w2 = (const float*)d_in[7];
    const float* b2 = (const float*)d_in[8];
    const float* w3 = (const float*)d_in[9];
    const float* b3 = (const float*)d_in[10];
    const float* gum = (const float*)d_in[11];
    const int* nsp   = (const int*)d_in[12];

    float* outP = (float*)d_out;          // pred_marking [2M]
    float* outL = outP + M_TOTAL;         // logits [64*512]

    double* wsd      = (double*)d_ws;
    double* partials = wsd;                         // 1024*32 doubles (region sized for 2048*32)
    double* totalp   = wsd + 2048 * 32;             // 1 double
    float*  vf       = (float*)(totalp + 1);        // 16 floats

    // Scratch tables live in the pred_marking output region; fully consumed by
    // k_steps before k_scores/k_scale overwrite outP.
    float* Rtab = outP;                   // 512*256 = 131072 floats
    float* w3R  = outP + 131072;          // 512*128 =  65536 floats
    float* w2R  = outP + 196608;          // 512*64  =  32768 floats

    // Fused front: reduce (1024 blocks) + expm (512) + weight relayout (516)
    k_front<<<K1_BLOCKS + 512 + 516, 256, 0, stream>>>(emb, vsrc, vtgt, partials,
                                                       tc, Rtab, w2, w3, w2R, w3R, totalp);
    k_steps<<<1, 512, 0, stream>>>(partials, w1, b1, b2, b3, w2R, w3R, Rtab, gum, nsp, outL, vf);
    k_scores<<<K3_BLOCKS, 256, 0, stream>>>(emb, vf, outP, totalp);
    k_scale<<<(M_TOTAL / 4 + 255) / 256, 256, 0, stream>>>(outP, totalp);
}

// Round 11
// 459.933 us; speedup vs baseline: 1.0136x; 1.0070x over previous
//
#include <hip/hip_runtime.h>

#define M_TOTAL   2000000
#define NT        512
#define K1_BLOCKS 1024
#define K3_BLOCKS 2048

__device__ __forceinline__ float rlf(float v, int l) {
    union { float f; int i; } u; u.f = v;
    u.i = __builtin_amdgcn_readlane(u.i, l);
    return u.f;
}

// Barrier with LDS-only drain: in-loop cross-thread data is exclusively LDS,
// so vmcnt (global outL stores / gum / Rtab loads) never needs draining.
__device__ __forceinline__ void bar_lds() {
    asm volatile("s_waitcnt lgkmcnt(0)" ::: "memory");
    __builtin_amdgcn_s_barrier();
    asm volatile("" ::: "memory");
}

// DPP helpers (register-crossbar cross-lane, ~4cy vs ~100cy for ds_bpermute shuffles).
#define DPPMAXU(m, ctrl) { unsigned _d = (unsigned)__builtin_amdgcn_update_dpp(0, (int)(m), (ctrl), 0xF, 0xF, true); \
                           if (_d > (m)) (m) = _d; }
#define DPPADDF(s, ctrl) { float _d = __int_as_float(__builtin_amdgcn_update_dpp(0, __float_as_int(s), (ctrl), 0xF, 0xF, true)); \
                           (s) += _d; }
// quad_perm controls: xor1 = [1,0,3,2] = 0xB1 ; xor2 = [2,3,0,1] = 0x4E
#define QP_XOR1 0xB1
#define QP_XOR2 0x4E

__device__ __forceinline__ unsigned orderf(float f) {
    unsigned u = __float_as_uint(f);
    return u ^ (((unsigned)((int)u >> 31)) | 0x80000000u);   // monotone float->uint
}

__device__ __forceinline__ uint2 pick2(uint2 a, uint2 b) {
    // larger key wins; equal key -> smaller index (first-index tiebreak)
    bool takeb = (b.x > a.x) || (b.x == a.x && b.y < a.y);
    return takeb ? b : a;
}

#define REP16(M)  M(0) M(1) M(2) M(3) M(4) M(5) M(6) M(7) M(8) M(9) M(10) M(11) M(12) M(13) M(14) M(15)
#define REP16B(M) M(16) M(17) M(18) M(19) M(20) M(21) M(22) M(23) M(24) M(25) M(26) M(27) M(28) M(29) M(30) M(31)

// Volatile load of 4 consecutive floats: performed exactly once, where written.
#define VLD4(dst, base, c) { const volatile float* _p = (base) + 4*(c); \
    dst.x = _p[0]; dst.y = _p[1]; dst.z = _p[2]; dst.w = _p[3]; }

// -------------------- K_front: fused reduce (blocks 0..1023) + expm (1024..1535) + relayout (1536..2051) --------------------
extern "C" __global__ __launch_bounds__(256)
void k_front(const float* __restrict__ emb, const float* __restrict__ vsrc,
             const float* __restrict__ vtgt, double* __restrict__ partials,
             const float* __restrict__ tc, float* __restrict__ Rtab,
             const float* __restrict__ w2g, const float* __restrict__ w3g,
             float* __restrict__ w2R, float* __restrict__ w3R,
             double* __restrict__ totalp)
{
    const int bid = blockIdx.x;
    const int t = threadIdx.x;

    if (bid < K1_BLOCKS) {
        // ---- partial sums of v_src@embs and v_target@embs (coalesced, f32 accum:
        //      only ~31 terms/accumulator so f32 is exact to ~1e-6) ----
        float aS[4], aT[4];
#pragma unroll
        for (int i = 0; i < 4; i++) { aS[i] = 0.0f; aT[i] = 0.0f; }

        const float4* emb4 = (const float4*)emb;
        for (long long f = (long long)bid * 256 + t; f < (long long)M_TOTAL * 4;
             f += (long long)K1_BLOCKS * 256) {
            float4 e = emb4[f];
            long long r = f >> 2;
            float sq = fmaf(e.x, e.x, fmaf(e.y, e.y, fmaf(e.z, e.z, e.w * e.w)));
            DPPADDF(sq, QP_XOR1)
            DPPADDF(sq, QP_XOR2)
            float invn = 1.0f / sqrtf(sq);
            float s = vsrc[r] * invn;
            float tv = vtgt[r] * invn;
            aS[0] = fmaf(s, e.x, aS[0]);  aS[1] = fmaf(s, e.y, aS[1]);
            aS[2] = fmaf(s, e.z, aS[2]);  aS[3] = fmaf(s, e.w, aS[3]);
            aT[0] = fmaf(tv, e.x, aT[0]); aT[1] = fmaf(tv, e.y, aT[1]);
            aT[2] = fmaf(tv, e.z, aT[2]); aT[3] = fmaf(tv, e.w, aT[3]);
        }
        double dS[4], dT[4];
#pragma unroll
        for (int i = 0; i < 4; i++) { dS[i] = (double)aS[i]; dT[i] = (double)aT[i]; }
#pragma unroll
        for (int i = 0; i < 4; i++) {
#pragma unroll
            for (int off = 32; off >= 4; off >>= 1) {
                dS[i] += __shfl_down(dS[i], off);
                dT[i] += __shfl_down(dT[i], off);
            }
        }
        __shared__ double lred[4][32];
        int lane = t & 63, wv = t >> 6;
        if (lane < 4) {
#pragma unroll
            for (int i = 0; i < 4; i++) {
                lred[wv][lane * 4 + i]      = dS[i];
                lred[wv][16 + lane * 4 + i] = dT[i];
            }
        }
        __syncthreads();
        if (t < 32) {
            double v = lred[0][t] + lred[1][t] + lred[2][t] + lred[3][t];
            partials[(long long)bid * 32 + t] = v;
        }
    } else if (bid < K1_BLOCKS + 512) {
        // ---- expm(gens[b]) via 16-term Taylor on the 16x16 skew matrix ----
        const int b = bid - K1_BLOCKS;
        const int i = t >> 4, j = t & 15;
        __shared__ float Om[256];
        __shared__ float Ms[256];

        const float* crow = tc + b * 120;
        float o = 0.0f;
        if (i < j)      o = -crow[(i * (31 - i)) / 2 + (j - i - 1)];
        else if (i > j) o =  crow[(j * (31 - j)) / 2 + (i - j - 1)];
        Om[t] = o;
        Ms[t] = o;
        float s = (i == j ? 1.0f : 0.0f) + o;   // S = I + Omega
        __syncthreads();

#pragma unroll
        for (int k = 2; k <= 16; k++) {
            float a0 = 0.0f, a1 = 0.0f, a2 = 0.0f, a3 = 0.0f;
#pragma unroll
            for (int m = 0; m < 4; m++) {
                a0 = fmaf(Om[i * 16 + m],      Ms[m * 16 + j],        a0);
                a1 = fmaf(Om[i * 16 + 4 + m],  Ms[(4 + m) * 16 + j],  a1);
                a2 = fmaf(Om[i * 16 + 8 + m],  Ms[(8 + m) * 16 + j],  a2);
                a3 = fmaf(Om[i * 16 + 12 + m], Ms[(12 + m) * 16 + j], a3);
            }
            float acc = ((a0 + a1) + (a2 + a3)) * (1.0f / (float)k);
            __syncthreads();
            Ms[t] = acc;
            s += acc;
            __syncthreads();
        }
        Rtab[b * 256 + t] = s;
    } else {
        // ---- per-thread-contiguous weight layouts for 512-thread k_steps (R4 layout) ----
        const int b = bid - (K1_BLOCKS + 512);   // 0..515
        if (b == 0 && t == 0) totalp[0] = 0.0;   // zero softmax denominator accumulator
        if (t >= 128) return;
        const int k = t;
        if (b < 512) {
            w3R[b * 128 + k] = w3g[k * 512 + b];
        } else {
            const int p2 = b - 512;     // 0..3
            const int j2 = k;           // 0..127
            for (int m = 0; m < 64; m++)
                w2R[(((p2 << 7) | j2) * 64) + m] = w2g[(64 * p2 + m) * 128 + j2];
        }
    }
}

// -------------------- K2: the sequential 64-step scan (1 block, 512 threads) --------------------
// 2-barrier step structure: L1 computed IN-WAVE (lane l of wave w computes
// h1[(w>>1)*64 + l] from register weights) -> feeds L2 directly with no h1 LDS
// round-trip and no barrier. Rotation replicated in all 8 waves (each wave needs
// vreg for its own L1). Barriers: after h2p write, after kidx write. Minimum for
// this dataflow (h2p mixes wave-pairs; kidx mixes all waves).
extern "C" __global__ __launch_bounds__(512)
__attribute__((amdgpu_waves_per_eu(2, 2)))
void k_steps(const double* __restrict__ partials,
             const float* __restrict__ w1g, const float* __restrict__ b1g,
             const float* __restrict__ b2g, const float* __restrict__ b3g,
             const float* __restrict__ w2R, const float* __restrict__ w3R,
             const float* __restrict__ Rtab, const float* __restrict__ gum,
             const int* __restrict__ nsp,
             float* __restrict__ outL, float* __restrict__ vf_out)
{
    __shared__ __align__(16) float h2p[512];
    __shared__ float xs[32];
    __shared__ float b2s[128];
    __shared__ uint2 kidx[8];
    __shared__ double dred[512];

    const int t = threadIdx.x;
    const int lane = t & 63;
    const int wv = t >> 6;
    const int j2 = t & 127, p2 = t >> 7;
    const int c1 = (p2 << 6) | lane;  // L1 column this thread computes: h1[p2*64 + lane]

    // ---- register-resident weights via volatile one-time loads ----
    const volatile float* w3v = (const volatile float*)(w3R + (size_t)t * 128);
    const volatile float* w2v = (const volatile float*)(w2R + (size_t)t * 64);
#define W3D(c) float4 w3_##c; VLD4(w3_##c, w3v, c)
    REP16(W3D) REP16B(W3D)
#undef W3D
#define W2D(c) float4 w2_##c; VLD4(w2_##c, w2v, c)
    REP16(W2D)
#undef W2D
    const float b3r = b3g[t];

    // w1 v-half column c1 in registers (16 floats, static indexing only)
    float w1r[16];
    {
        const volatile float* w1v = (const volatile float*)w1g;
#pragma unroll
        for (int m = 0; m < 16; m++) w1r[m] = w1v[m * 256 + c1];
    }
    if (t < 128) b2s[t] = b2g[t];

    // warm Rtab (512 KB) into this XCD's L2 so per-step rotation loads hit L2 not HBM
    float warm = 0.0f;
    for (int i = t; i < 512 * 256 / 4; i += 512) {
        float4 rv = ((const float4*)Rtab)[i];
        warm += (rv.x + rv.y) + (rv.z + rv.w);
    }

    // stage-2 reduce of K1 partials, coalesced: flat[f] has column f%32
    {
        double v = 0.0;
#pragma unroll 4
        for (int i = 0; i < (K1_BLOCKS * 32) / 512; i++) v += partials[i * 512 + t];
        dred[t] = v;
    }

    int ns = nsp[0];
    if (ns > 64) ns = 64;
    if (ns < 0)  ns = 0;
    if (ns == -2147483647) vf_out[0] = warm;   // never true; defeats DCE

    __syncthreads();
    if (t < 32) {
        double s = 0.0;
#pragma unroll
        for (int j = 0; j < 16; j++) s += dred[t + 32 * j];
        xs[t] = (float)s;                      // xs[0:16]=v_cur, xs[16:32]=v_tgt
    }
    __syncthreads();

    // b1_eff = b1 + v_tgt @ w1[16:32] for column c1; v replicated in ALL waves
    float b1e;
    {
        float a = b1g[c1];
#pragma unroll
        for (int m = 0; m < 16; m++)
            a = fmaf(xs[16 + m], w1g[(16 + m) * 256 + c1], a);
        b1e = a;
    }
    float vreg = xs[lane & 15];        // lane l holds v[l&15] (only lanes 0-15 ever read)

    if (ns == 0 && t < 16) vf_out[t] = xs[t];

    for (int step = 0; step < ns; step++) {
        float gv = gum[step * 512 + t];       // hoisted global load (needed at argmax)

        // ---- layer 1 (in-wave, no LDS, no barrier): h1seg = relu(v @ w1[:,c1] + b1e);
        //      lane l of wave w holds h1[(w>>1)*64 + l] -- exactly what L2 consumes ----
        float h1seg;
        {
            float m0 = rlf(vreg, 0),  m1 = rlf(vreg, 1),  m2 = rlf(vreg, 2),  m3 = rlf(vreg, 3);
            float m4 = rlf(vreg, 4),  m5 = rlf(vreg, 5),  m6 = rlf(vreg, 6),  m7 = rlf(vreg, 7);
            float a0 = fmaf(m0, w1r[0], 0.0f), a1 = fmaf(m1, w1r[1], 0.0f);
            a0 = fmaf(m2, w1r[2], a0); a1 = fmaf(m3, w1r[3], a1);
            a0 = fmaf(m4, w1r[4], a0); a1 = fmaf(m5, w1r[5], a1);
            a0 = fmaf(m6, w1r[6], a0); a1 = fmaf(m7, w1r[7], a1);
            float n0 = rlf(vreg, 8),  n1 = rlf(vreg, 9),  n2 = rlf(vreg, 10), n3 = rlf(vreg, 11);
            float n4 = rlf(vreg, 12), n5 = rlf(vreg, 13), n6 = rlf(vreg, 14), n7 = rlf(vreg, 15);
            a0 = fmaf(n0, w1r[8],  a0); a1 = fmaf(n1, w1r[9],  a1);
            a0 = fmaf(n2, w1r[10], a0); a1 = fmaf(n3, w1r[11], a1);
            a0 = fmaf(n4, w1r[12], a0); a1 = fmaf(n5, w1r[13], a1);
            a0 = fmaf(n6, w1r[14], a0); a1 = fmaf(n7, w1r[15], a1);
            h1seg = fmaxf((a0 + a1) + b1e, 0.0f);
        }

        // ---- layer 2 partials: 128 outputs x 4-way K split; h1seg from register ----
        {
            float a0 = 0.0f, a1 = 0.0f, a2 = 0.0f, a3 = 0.0f;
#define L2B(c0, c1c) { \
            float m0 = rlf(h1seg, 4*(c0)+0),  m1 = rlf(h1seg, 4*(c0)+1); \
            float m2 = rlf(h1seg, 4*(c0)+2),  m3 = rlf(h1seg, 4*(c0)+3); \
            float m4 = rlf(h1seg, 4*(c1c)+0), m5 = rlf(h1seg, 4*(c1c)+1); \
            float m6 = rlf(h1seg, 4*(c1c)+2), m7 = rlf(h1seg, 4*(c1c)+3); \
            a0 = fmaf(m0, w2_##c0.x, a0);  a1 = fmaf(m1, w2_##c0.y, a1); \
            a2 = fmaf(m2, w2_##c0.z, a2);  a3 = fmaf(m3, w2_##c0.w, a3); \
            a0 = fmaf(m4, w2_##c1c.x, a0); a1 = fmaf(m5, w2_##c1c.y, a1); \
            a2 = fmaf(m6, w2_##c1c.z, a2); a3 = fmaf(m7, w2_##c1c.w, a3); }
            L2B(0, 1)  L2B(2, 3)  L2B(4, 5)  L2B(6, 7)
            L2B(8, 9)  L2B(10, 11) L2B(12, 13) L2B(14, 15)
#undef L2B
            h2p[(p2 << 7) | j2] = (a0 + a1) + (a2 + a3);
        }
        bar_lds();

        // ---- layer 3: reconstruct h2 in-lane (fused reduce), then logits ----
        float lg;
        {
            float h2lo = fmaxf(((h2p[lane] + h2p[128 + lane]) +
                                (h2p[256 + lane] + h2p[384 + lane])) + b2s[lane], 0.0f);
            float h2hi = fmaxf(((h2p[64 + lane] + h2p[192 + lane]) +
                                (h2p[320 + lane] + h2p[448 + lane])) + b2s[64 + lane], 0.0f);
            float lg0 = 0.0f, lg1 = 0.0f, lg2 = 0.0f, lg3 = 0.0f;
#define L3BLO(c0, c1c) { \
            float m0 = rlf(h2lo, 4*(c0)+0),  m1 = rlf(h2lo, 4*(c0)+1); \
            float m2 = rlf(h2lo, 4*(c0)+2),  m3 = rlf(h2lo, 4*(c0)+3); \
            float m4 = rlf(h2lo, 4*(c1c)+0), m5 = rlf(h2lo, 4*(c1c)+1); \
            float m6 = rlf(h2lo, 4*(c1c)+2), m7 = rlf(h2lo, 4*(c1c)+3); \
            lg0 = fmaf(m0, w3_##c0.x, lg0);  lg1 = fmaf(m1, w3_##c0.y, lg1); \
            lg2 = fmaf(m2, w3_##c0.z, lg2);  lg3 = fmaf(m3, w3_##c0.w, lg3); \
            lg0 = fmaf(m4, w3_##c1c.x, lg0); lg1 = fmaf(m5, w3_##c1c.y, lg1); \
            lg2 = fmaf(m6, w3_##c1c.z, lg2); lg3 = fmaf(m7, w3_##c1c.w, lg3); }
#define L3BHI(c0, c1c) { \
            float m0 = rlf(h2hi, 4*(c0)-64), m1 = rlf(h2hi, 4*(c0)-63); \
            float m2 = rlf(h2hi, 4*(c0)-62), m3 = rlf(h2hi, 4*(c0)-61); \
            float m4 = rlf(h2hi, 4*(c1c)-64), m5 = rlf(h2hi, 4*(c1c)-63); \
            float m6 = rlf(h2hi, 4*(c1c)-62), m7 = rlf(h2hi, 4*(c1c)-61); \
            lg0 = fmaf(m0, w3_##c0.x, lg0);  lg1 = fmaf(m1, w3_##c0.y, lg1); \
            lg2 = fmaf(m2, w3_##c0.z, lg2);  lg3 = fmaf(m3, w3_##c0.w, lg3); \
            lg0 = fmaf(m4, w3_##c1c.x, lg0); lg1 = fmaf(m5, w3_##c1c.y, lg1); \
            lg2 = fmaf(m6, w3_##c1c.z, lg2); lg3 = fmaf(m7, w3_##c1c.w, lg3); }
            L3BLO(0, 1)   L3BLO(2, 3)   L3BLO(4, 5)   L3BLO(6, 7)
            L3BLO(8, 9)   L3BLO(10, 11) L3BLO(12, 13) L3BLO(14, 15)
            L3BHI(16, 17) L3BHI(18, 19) L3BHI(20, 21) L3BHI(22, 23)
            L3BHI(24, 25) L3BHI(26, 27) L3BHI(28, 29) L3BHI(30, 31)
#undef L3BLO
#undef L3BHI
            lg = ((lg0 + lg1) + (lg2 + lg3)) + b3r;
        }
        outL[step * 512 + t] = lg;   // fire-and-forget; lgkm barriers don't drain vmcnt

        // ---- argmax(logits + gumbel): DPP wave-max + ballot (no bpermute chain) ----
        {
            unsigned ok = orderf(lg + gv);
            unsigned m = ok;
            DPPMAXU(m, 0x111)   // row_shr:1
            DPPMAXU(m, 0x112)   // row_shr:2
            DPPMAXU(m, 0x114)   // row_shr:4
            DPPMAXU(m, 0x118)   // row_shr:8  -> lane15 of each row has row max
            DPPMAXU(m, 0x142)   // row_bcast15
            DPPMAXU(m, 0x143)   // row_bcast31 -> lane63 has wave max
            unsigned wmax = (unsigned)__builtin_amdgcn_readlane((int)m, 63);
            unsigned long long mask = __ballot(ok == wmax);
            if (lane == 0) {
                uint2 kv; kv.x = wmax; kv.y = (unsigned)(wv * 64 + (__ffsll(mask) - 1));
                kidx[wv] = kv;
            }
        }
        bar_lds();

        // ---- rotation: ALL 8 waves, lanes 0-15; v' = normalize(R[bi] @ v) ----
        if (lane < 16) {
            uint2 K0, K1, K2, K3, K4, K5, K6, K7;
            { uint4 a = *(const uint4*)&kidx[0]; K0.x=a.x; K0.y=a.y; K1.x=a.z; K1.y=a.w; }
            { uint4 a = *(const uint4*)&kidx[2]; K2.x=a.x; K2.y=a.y; K3.x=a.z; K3.y=a.w; }
            { uint4 a = *(const uint4*)&kidx[4]; K4.x=a.x; K4.y=a.y; K5.x=a.z; K5.y=a.w; }
            { uint4 a = *(const uint4*)&kidx[6]; K6.x=a.x; K6.y=a.y; K7.x=a.z; K7.y=a.w; }
            uint2 w01 = pick2(K0, K1), w23 = pick2(K2, K3);
            uint2 w45 = pick2(K4, K5), w67 = pick2(K6, K7);
            uint2 win = pick2(pick2(w01, w23), pick2(w45, w67));
            const int bi = (int)win.y;

            const float4* rp = (const float4*)(Rtab + (size_t)bi * 256 + lane * 16);
            float4 ra = rp[0], rb = rp[1], rc = rp[2], rd = rp[3];
            // batch-16 readlanes, then 4 independent fma chains, tree-sum
            float v0r = rlf(vreg, 0),  v1r = rlf(vreg, 1),  v2r = rlf(vreg, 2),  v3r = rlf(vreg, 3);
            float v4r = rlf(vreg, 4),  v5r = rlf(vreg, 5),  v6r = rlf(vreg, 6),  v7r = rlf(vreg, 7);
            float v8r = rlf(vreg, 8),  v9r = rlf(vreg, 9),  vAr = rlf(vreg, 10), vBr = rlf(vreg, 11);
            float vCr = rlf(vreg, 12), vDr = rlf(vreg, 13), vEr = rlf(vreg, 14), vFr = rlf(vreg, 15);
            float p0 = ra.x * v0r;
            float p1 = rb.x * v4r;
            float p2r = rc.x * v8r;
            float p3 = rd.x * vCr;
            p0 = fmaf(ra.y, v1r, p0);
            p1 = fmaf(rb.y, v5r, p1);
            p2r = fmaf(rc.y, v9r, p2r);
            p3 = fmaf(rd.y, vDr, p3);
            p0 = fmaf(ra.z, v2r, p0);
            p1 = fmaf(rb.z, v6r, p1);
            p2r = fmaf(rc.z, vAr, p2r);
            p3 = fmaf(rd.z, vEr, p3);
            p0 = fmaf(ra.w, v3r, p0);
            p1 = fmaf(rb.w, v7r, p1);
            p2r = fmaf(rc.w, vBr, p2r);
            p3 = fmaf(rd.w, vFr, p3);
            float pr = (p0 + p1) + (p2r + p3);

            float s2 = pr * pr;                 // sum over lanes 0-15 via DPP row-shr
            DPPADDF(s2, 0x111)
            DPPADDF(s2, 0x112)
            DPPADDF(s2, 0x114)
            DPPADDF(s2, 0x118)                  // lane15 = full row sum
            float n2 = rlf(s2, 15);
            float invn = 1.0f / sqrtf(n2);
            vreg = pr * invn;                   // lane l holds v'[l], all 8 waves consistent
            if (step == ns - 1 && t < 16) vf_out[t] = vreg;
        }
        // no barrier here: next L1 uses only own-wave registers; h2p(s+1) writes are
        // separated from this step's h2p reads by the barrier after the L2 phase.
    }
}

// -------------------- K3: scores = exp(dot(v_fin, emb_row_norm)); block sums -> atomic total --------------------
extern "C" __global__ __launch_bounds__(256)
void k_scores(const float* __restrict__ emb, const float* __restrict__ vf16,
              float* __restrict__ outP, double* __restrict__ totalp)
{
    __shared__ float vfs[16];
    const int tid = threadIdx.x;
    const int bid = blockIdx.x;
    const int q = tid & 3;
    if (tid < 16) vfs[tid] = vf16[tid];
    __syncthreads();
    float v0 = vfs[q * 4 + 0], v1 = vfs[q * 4 + 1], v2 = vfs[q * 4 + 2], v3 = vfs[q * 4 + 3];

    const float4* emb4 = (const float4*)emb;
    double bsum = 0.0;
    for (long long f = (long long)bid * 256 + tid; f < (long long)M_TOTAL * 4;
         f += (long long)K3_BLOCKS * 256) {
        float4 e = emb4[f];
        long long r = f >> 2;
        float sq = fmaf(e.x, e.x, fmaf(e.y, e.y, fmaf(e.z, e.z, e.w * e.w)));
        float d  = fmaf(e.x, v0, fmaf(e.y, v1, fmaf(e.z, v2, e.w * v3)));
        DPPADDF(sq, QP_XOR1)
        DPPADDF(d,  QP_XOR1)
        DPPADDF(sq, QP_XOR2)
        DPPADDF(d,  QP_XOR2)
        float ex = expf(d / sqrtf(sq));   // |score| <= 1, no overflow; softmax shift cancels
        if (q == 0) {
            outP[r] = ex;
            bsum += (double)ex;
        }
    }
#pragma unroll
    for (int off = 4; off <= 32; off <<= 1) bsum += __shfl_down(bsum, off);
    __shared__ double lred[4];
    if ((tid & 63) == 0) lred[tid >> 6] = bsum;
    __syncthreads();
    if (tid == 0) atomicAdd(totalp, lred[0] + lred[1] + lred[2] + lred[3]);
}

// -------------------- K5: normalize --------------------
extern "C" __global__ __launch_bounds__(256)
void k_scale(float* __restrict__ outP, const double* __restrict__ totalp)
{
    const float inv = 1.0f / (float)totalp[0];
    long long r4 = (long long)blockIdx.x * 256 + threadIdx.x;
    if (r4 < M_TOTAL / 4) {
        float4* p = (float4*)outP;
        float4 v = p[r4];
        v.x *= inv; v.y *= inv; v.z *= inv; v.w *= inv;
        p[r4] = v;
    }
}

extern "C" void kernel_launch(void* const* d_in, const int* in_sizes, int n_in,
                              void* d_out, int out_size, void* d_ws, size_t ws_size,
                              hipStream_t stream)
{
    const float* vsrc = (const float*)d_in[0];
    const float* vtgt = (const float*)d_in[1];
    const float* emb  = (const float*)d_in[2];
    const float* tc   = (const float*)d_in[3];
    // d_in[4] = bases: structure is hard-coded (omega[i][j] = -/+ coeffs[t*, k(i,j)])
    const float* w1 = (const float*)d_in[5];
    const float* b1 = (const float*)d_in[6];
    const float* w2 = (const float*)d_in[7];
    const float* b2 = (const float*)d_in[8];
    const float* w3 = (const float*)d_in[9];
    const float* b3 = (const float*)d_in[10];
    const float* gum = (const float*)d_in[11];
    const int* nsp   = (const int*)d_in[12];

    float* outP = (float*)d_out;          // pred_marking [2M]
    float* outL = outP + M_TOTAL;         // logits [64*512]

    double* wsd      = (double*)d_ws;
    double* partials = wsd;                         // 1024*32 doubles (region sized for 2048*32)
    double* totalp   = wsd + 2048 * 32;             // 1 double
    float*  vf       = (float*)(totalp + 1);        // 16 floats

    // Scratch tables live in the pred_marking output region; fully consumed by
    // k_steps before k_scores/k_scale overwrite outP.
    float* Rtab = outP;                   // 512*256 = 131072 floats
    float* w3R  = outP + 131072;          // 512*128 =  65536 floats
    float* w2R  = outP + 196608;          // 512*64  =  32768 floats

    // Fused front: reduce (1024 blocks) + expm (512) + weight relayout (516)
    k_front<<<K1_BLOCKS + 512 + 516, 256, 0, stream>>>(emb, vsrc, vtgt, partials,
                                                       tc, Rtab, w2, w3, w2R, w3R, totalp);
    k_steps<<<1, 512, 0, stream>>>(partials, w1, b1, b2, b3, w2R, w3R, Rtab, gum, nsp, outL, vf);
    k_scores<<<K3_BLOCKS, 256, 0, stream>>>(emb, vf, outP, totalp);
    k_scale<<<(M_TOTAL / 4 + 255) / 256, 256, 0, stream>>>(outP, totalp);
}